// Round 1
// baseline (43198.822 us; speedup 1.0000x reference)
//
#include <hip/hip_runtime.h>
#include <hip/hip_bf16.h>
#include <math.h>

#define VSZ 50257
#define TSEQ 1024
#define DMODEL 768
#define NH 12
#define HS 64
#define NL 12
#define BATCH 4
#define BT (BATCH * TSEQ)   // 4096
#define EPS 1e-5f

// ---------------- embedding ----------------
__global__ void embed_kernel(const int* __restrict__ idx,
                             const float* __restrict__ tok_emb,
                             const float* __restrict__ pos_emb,
                             float* __restrict__ x) {
  int i = blockIdx.x * blockDim.x + threadIdx.x;  // over BT*D
  if (i >= BT * DMODEL) return;
  int d = i % DMODEL;
  int bt = i / DMODEL;
  int t = bt % TSEQ;
  int tok = idx[bt];
  x[i] = tok_emb[(size_t)tok * DMODEL + d] + pos_emb[(size_t)t * DMODEL + d];
}

// ---------------- layernorm (one block of 256 per row of 768) ----------------
__global__ void ln_kernel(const float* __restrict__ x,
                          const float* __restrict__ s,
                          const float* __restrict__ b,
                          float* __restrict__ out) {
  int row = blockIdx.x;
  int tid = threadIdx.x;
  const float* xr = x + (size_t)row * DMODEL;
  float v0 = xr[tid], v1 = xr[tid + 256], v2 = xr[tid + 512];
  __shared__ float red[256];
  red[tid] = v0 + v1 + v2;
  __syncthreads();
  for (int st = 128; st > 0; st >>= 1) {
    if (tid < st) red[tid] += red[tid + st];
    __syncthreads();
  }
  float mean = red[0] * (1.0f / DMODEL);
  __syncthreads();
  float d0 = v0 - mean, d1 = v1 - mean, d2 = v2 - mean;
  red[tid] = d0 * d0 + d1 * d1 + d2 * d2;
  __syncthreads();
  for (int st = 128; st > 0; st >>= 1) {
    if (tid < st) red[tid] += red[tid + st];
    __syncthreads();
  }
  float rstd = rsqrtf(red[0] * (1.0f / DMODEL) + EPS);
  float* outr = out + (size_t)row * DMODEL;
  outr[tid]       = d0 * rstd * s[tid]       + b[tid];
  outr[tid + 256] = d1 * rstd * s[tid + 256] + b[tid + 256];
  outr[tid + 512] = d2 * rstd * s[tid + 512] + b[tid + 512];
}

// ---------------- generic fp32 GEMM: C = A(MxK) @ B(KxN) [+bias] [+res] [relu] ----------------
// 64x64 tile, BK=16, 256 threads, 4x4 per thread.
template <bool BIAS, bool RES, bool RELU>
__global__ void gemm_kernel(const float* __restrict__ A,
                            const float* __restrict__ Bm,
                            const float* __restrict__ bias,
                            const float* __restrict__ res,
                            float* __restrict__ C,
                            int M, int N, int K) {
  __shared__ float As[16][65];   // [k][m], padded
  __shared__ float Bs[16][64];   // [k][n]
  const int bn = blockIdx.x * 64;
  const int bm = blockIdx.y * 64;
  const int tid = threadIdx.x;
  const int tx = tid & 15;        // 0..15  -> n group
  const int ty = tid >> 4;        // 0..15  -> m group
  float acc[4][4] = {};

  const int la_k = tid & 15;      // A-load k
  const int la_m = tid >> 4;      // A-load m base
  const int lb_n = tid & 63;      // B-load n
  const int lb_k = tid >> 6;      // B-load k base (0..3)

  for (int k0 = 0; k0 < K; k0 += 16) {
#pragma unroll
    for (int it = 0; it < 4; ++it) {
      As[la_k][la_m + it * 16] = A[(size_t)(bm + la_m + it * 16) * K + k0 + la_k];
    }
    int gn = bn + lb_n;
#pragma unroll
    for (int it = 0; it < 4; ++it) {
      int kk = lb_k + it * 4;
      Bs[kk][lb_n] = (gn < N) ? Bm[(size_t)(k0 + kk) * N + gn] : 0.0f;
    }
    __syncthreads();
#pragma unroll
    for (int k = 0; k < 16; ++k) {
      float a[4], bb[4];
#pragma unroll
      for (int i = 0; i < 4; ++i) a[i] = As[k][ty * 4 + i];
#pragma unroll
      for (int j = 0; j < 4; ++j) bb[j] = Bs[k][tx * 4 + j];
#pragma unroll
      for (int i = 0; i < 4; ++i)
#pragma unroll
        for (int j = 0; j < 4; ++j) acc[i][j] += a[i] * bb[j];
    }
    __syncthreads();
  }

#pragma unroll
  for (int i = 0; i < 4; ++i) {
    int gm = bm + ty * 4 + i;
#pragma unroll
    for (int j = 0; j < 4; ++j) {
      int gn = bn + tx * 4 + j;
      if (gn < N) {
        float vv = acc[i][j];
        if (BIAS) vv += bias[gn];
        if (RES) vv += res[(size_t)gm * N + gn];
        if (RELU) vv = fmaxf(vv, 0.0f);
        C[(size_t)gm * N + gn] = vv;
      }
    }
  }
}

// ---------------- fused causal attention, online softmax ----------------
// one wave (64 lanes) per (b,h,t) query row; lane = head-dim element (HS=64)
__global__ void attn_kernel(const float* __restrict__ q,
                            const float* __restrict__ k,
                            const float* __restrict__ v,
                            float* __restrict__ o) {
  int wave = (blockIdx.x * blockDim.x + threadIdx.x) >> 6;
  int lane = threadIdx.x & 63;
  int t = wave % TSEQ;
  int bh = wave / TSEQ;
  int h = bh % NH;
  int b = bh / NH;
  const size_t qoff = ((size_t)(b * TSEQ + t) * DMODEL) + h * HS;
  float qe = q[qoff + lane] * 0.125f;  // HS^-0.5
  const float* kb = k + ((size_t)b * TSEQ) * DMODEL + h * HS;
  const float* vb = v + ((size_t)b * TSEQ) * DMODEL + h * HS;
  float m = -INFINITY, l = 0.0f, acc = 0.0f;
  for (int s = 0; s <= t; ++s) {
    float prod = qe * kb[(size_t)s * DMODEL + lane];
#pragma unroll
    for (int off = 32; off > 0; off >>= 1) prod += __shfl_xor(prod, off, 64);
    float sc = prod;
    float mn = fmaxf(m, sc);
    float corr = __expf(m - mn);
    float p = __expf(sc - mn);
    l = l * corr + p;
    acc = acc * corr + p * vb[(size_t)s * DMODEL + lane];
    m = mn;
  }
  o[qoff + lane] = acc / l;
}

// ---------------- loss: per-row log-softmax NLL, atomic accumulate ----------------
__global__ void loss_kernel(const float* __restrict__ logits,
                            const int* __restrict__ targets,
                            float* __restrict__ acc) {
  int row = blockIdx.x;
  int tid = threadIdx.x;
  const float* lr = logits + (size_t)row * VSZ;
  float mx = -INFINITY;
  for (int i = tid; i < VSZ; i += 256) mx = fmaxf(mx, lr[i]);
  __shared__ float red[256];
  red[tid] = mx;
  __syncthreads();
  for (int st = 128; st > 0; st >>= 1) {
    if (tid < st) red[tid] = fmaxf(red[tid], red[tid + st]);
    __syncthreads();
  }
  mx = red[0];
  __syncthreads();
  float sum = 0.0f;
  for (int i = tid; i < VSZ; i += 256) sum += __expf(lr[i] - mx);
  red[tid] = sum;
  __syncthreads();
  for (int st = 128; st > 0; st >>= 1) {
    if (tid < st) red[tid] += red[tid + st];
    __syncthreads();
  }
  if (tid == 0) {
    int tgt = targets[row];
    float lp = lr[tgt] - mx - logf(red[0]);
    atomicAdd(acc, -lp);
  }
}

__global__ void loss_final(const float* __restrict__ acc, float* __restrict__ out) {
  out[0] = acc[0] * (1.0f / BT);
}

// ---------------- launch ----------------
extern "C" void kernel_launch(void* const* d_in, const int* in_sizes, int n_in,
                              void* d_out, int out_size, void* d_ws, size_t ws_size,
                              hipStream_t stream) {
  const int*   idx     = (const int*)d_in[0];
  const int*   targets = (const int*)d_in[1];
  const float* tok_emb = (const float*)d_in[2];
  const float* pos_emb = (const float*)d_in[3];
  const float* ln1_s   = (const float*)d_in[4];
  const float* ln1_b   = (const float*)d_in[5];
  const float* Wq      = (const float*)d_in[6];
  const float* Wk      = (const float*)d_in[7];
  const float* Wv      = (const float*)d_in[8];
  const float* Wo      = (const float*)d_in[9];
  const float* bo      = (const float*)d_in[10];
  const float* ln2_s   = (const float*)d_in[11];
  const float* ln2_b   = (const float*)d_in[12];
  const float* W1      = (const float*)d_in[13];
  const float* b1      = (const float*)d_in[14];
  const float* W2      = (const float*)d_in[15];
  const float* b2      = (const float*)d_in[16];
  const float* lnf_s   = (const float*)d_in[17];
  const float* lnf_b   = (const float*)d_in[18];
  const float* lm_W    = (const float*)d_in[19];
  const float* lm_b    = (const float*)d_in[20];

  float* logits = (float*)d_out;               // BT*VSZ
  float* loss   = logits + (size_t)BT * VSZ;   // 1

  float* ws = (float*)d_ws;
  float* x  = ws;                       // BT*D
  float* h  = x  + (size_t)BT * DMODEL; // BT*D
  float* q  = h  + (size_t)BT * DMODEL;
  float* k  = q  + (size_t)BT * DMODEL;
  float* v  = k  + (size_t)BT * DMODEL;
  float* ao = v  + (size_t)BT * DMODEL;
  float* u  = ao + (size_t)BT * DMODEL; // BT*4D
  float* lacc = u + (size_t)BT * 4 * DMODEL;  // 1

  // embedding
  {
    int n = BT * DMODEL;
    embed_kernel<<<(n + 255) / 256, 256, 0, stream>>>(idx, tok_emb, pos_emb, x);
  }

  dim3 gD((DMODEL + 63) / 64, BT / 64);      // N=768
  dim3 gF((4 * DMODEL + 63) / 64, BT / 64);  // N=3072
  dim3 gV((VSZ + 63) / 64, BT / 64);         // N=50257

  for (int l = 0; l < NL; ++l) {
    const float* wq = Wq + (size_t)l * DMODEL * DMODEL;
    const float* wk = Wk + (size_t)l * DMODEL * DMODEL;
    const float* wv = Wv + (size_t)l * DMODEL * DMODEL;
    const float* wo = Wo + (size_t)l * DMODEL * DMODEL;
    const float* w1 = W1 + (size_t)l * DMODEL * 4 * DMODEL;
    const float* w2 = W2 + (size_t)l * 4 * DMODEL * DMODEL;

    // ln1
    ln_kernel<<<BT, 256, 0, stream>>>(x, ln1_s + l * DMODEL, ln1_b + l * DMODEL, h);
    // qkv
    gemm_kernel<false, false, false><<<gD, 256, 0, stream>>>(h, wq, nullptr, nullptr, q, BT, DMODEL, DMODEL);
    gemm_kernel<false, false, false><<<gD, 256, 0, stream>>>(h, wk, nullptr, nullptr, k, BT, DMODEL, DMODEL);
    gemm_kernel<false, false, false><<<gD, 256, 0, stream>>>(h, wv, nullptr, nullptr, v, BT, DMODEL, DMODEL);
    // attention
    {
      int waves = BATCH * NH * TSEQ;             // 49152
      attn_kernel<<<waves / 4, 256, 0, stream>>>(q, k, v, ao);
    }
    // x = x + ao @ Wo + bo
    gemm_kernel<true, true, false><<<gD, 256, 0, stream>>>(ao, wo, bo + l * DMODEL, x, x, BT, DMODEL, DMODEL);
    // ln2
    ln_kernel<<<BT, 256, 0, stream>>>(x, ln2_s + l * DMODEL, ln2_b + l * DMODEL, h);
    // u = relu(h @ W1 + b1)
    gemm_kernel<true, false, true><<<gF, 256, 0, stream>>>(h, w1, b1 + (size_t)l * 4 * DMODEL, nullptr, u, BT, 4 * DMODEL, DMODEL);
    // x = x + u @ W2 + b2
    gemm_kernel<true, true, false><<<gD, 256, 0, stream>>>(u, w2, b2 + l * DMODEL, x, x, BT, DMODEL, 4 * DMODEL);
  }

  // final LN
  ln_kernel<<<BT, 256, 0, stream>>>(x, lnf_s, lnf_b, h);
  // logits = h @ lm_W + lm_b
  gemm_kernel<true, false, false><<<gV, 256, 0, stream>>>(h, lm_W, lm_b, nullptr, logits, BT, VSZ, DMODEL);

  // loss
  hipMemsetAsync(lacc, 0, sizeof(float), stream);
  loss_kernel<<<BT, 256, 0, stream>>>(logits, targets, lacc);
  loss_final<<<1, 1, 0, stream>>>(lacc, loss);
}